// Round 1
// baseline (615.737 us; speedup 1.0000x reference)
//
#include <hip/hip_runtime.h>
#include <hip/hip_bf16.h>
#include <math.h>

#define LN_EPS 1e-5f

typedef __attribute__((ext_vector_type(4))) float f4_t;
typedef __attribute__((ext_vector_type(8))) short bf8_t;

__device__ __forceinline__ unsigned short f2bf(float x) {
    unsigned u = __builtin_bit_cast(unsigned, x);
    unsigned r = (u + 0x7FFFu + ((u >> 16) & 1u)) >> 16;
    return (unsigned short)r;
}
__device__ __forceinline__ float bf2f(unsigned short u) {
    return __builtin_bit_cast(float, ((unsigned)u) << 16);
}

// ---------------- kernel 1: cast W1/W2 f32 -> bf16 (flat, layout preserved) ----
__global__ void cvt_kernel(const float* __restrict__ W1, const float* __restrict__ W2,
                           unsigned short* __restrict__ W1b, unsigned short* __restrict__ W2b) {
    int i = blockIdx.x * 256 + threadIdx.x;   // grid covers 262144 exactly
    W1b[i] = f2bf(W1[i]);
    W2b[i] = f2bf(W2[i]);
}

// ---------------- kernel 2: 4x4 block pool: fs[n][k][c] ------------------------
__global__ void pool_kernel(const float* __restrict__ feature, float* __restrict__ fs) {
    int bk = blockIdx.x;           // n*400 + k
    int n = bk / 400, k = bk % 400;
    int c = threadIdx.x;
    int h = k / 20, w = k % 20;
    const float* base = feature + ((size_t)(n * 256 + c)) * 6400 + (h * 4) * 80 + w * 4;
    float s = 0.f;
#pragma unroll
    for (int dh = 0; dh < 4; ++dh) {
        float4 v = *reinterpret_cast<const float4*>(base + dh * 80);
        s += v.x + v.y + v.z + v.w;
    }
    fs[((size_t)n * 400 + k) * 256 + c] = s;
}

// ---------------- kernel 3: r[n][i][c] = sum_k weight[n][i][k] * fs[n][k][c] ---
__global__ void att_kernel(const float* __restrict__ wgt, const float* __restrict__ fs,
                           float* __restrict__ r) {
    __shared__ float fsl[16][256];
    __shared__ float wl[8][16];
    int b = blockIdx.x;
    int n = b / 50, i0 = (b % 50) * 8;
    int tid = threadIdx.x;
    const float* wbase = wgt + (size_t)n * 400 * 400;
    const float* fsbase = fs + (size_t)n * 400 * 256;
    float acc[8] = {0.f, 0.f, 0.f, 0.f, 0.f, 0.f, 0.f, 0.f};
    for (int k0 = 0; k0 < 400; k0 += 16) {
#pragma unroll
        for (int jj = 0; jj < 16; ++jj)
            fsl[jj][tid] = fsbase[(size_t)(k0 + jj) * 256 + tid];
        if (tid < 128)
            wl[tid >> 4][tid & 15] = wbase[(size_t)(i0 + (tid >> 4)) * 400 + k0 + (tid & 15)];
        __syncthreads();
#pragma unroll
        for (int kk = 0; kk < 16; ++kk) {
            float f = fsl[kk][tid];
#pragma unroll
            for (int ii = 0; ii < 8; ++ii) acc[ii] += wl[ii][kk] * f;
        }
        __syncthreads();
    }
#pragma unroll
    for (int ii = 0; ii < 8; ++ii)
        r[((size_t)n * 400 + i0 + ii) * 256 + tid] = acc[ii];
}

// ---------------- kernel 4: fused residual+att + LN1 + MLP(GELU) + LN2 ---------
// block = 64 tokens (one n, contiguous p), 256 threads = 4 waves, wave w owns token
// rows 16w..16w+15 for the MFMA phase. xt/ht are XOR-swizzled bf16 LDS tiles.
__global__ __launch_bounds__(256, 2) void main_kernel(
    const float* __restrict__ feat, const float* __restrict__ r,
    const float* __restrict__ ln1g, const float* __restrict__ ln1b,
    const unsigned short* __restrict__ W1b, const float* __restrict__ b1,
    const unsigned short* __restrict__ W2b, const float* __restrict__ b2,
    const float* __restrict__ ln2g, const float* __restrict__ ln2b,
    float* __restrict__ out) {
    __shared__ unsigned short xt[64 * 256];   // [t][c] swizzled, 32 KB
    __shared__ unsigned short ht[64 * 128];   // [t][f] swizzled, 16 KB
    __shared__ float part[2][4][64];
    __shared__ float stat[2][64];

    int bid = blockIdx.x;
    int n = bid / 100;
    int p0 = (bid % 100) * 64;
    int tid = threadIdx.x;
    int lane = tid & 63;
    int q = tid >> 6;                     // wave id
    int t = lane;                         // token row this thread loads
    int p = p0 + t;
    int iatt = ((p / 80) >> 2) * 20 + ((p % 80) >> 2);

    // ---- phase 1: x = residual + att, LN1 stats ----
    const float* fbase = feat + ((size_t)(n * 256 + q * 64)) * 6400 + p;
    const float* rrow = r + ((size_t)(n * 400 + iatt)) * 256 + q * 64;
    float xv[64];
    float s1 = 0.f, s2 = 0.f;
#pragma unroll
    for (int j = 0; j < 64; ++j) {
        float v = fbase[(size_t)j * 6400] + rrow[j];
        xv[j] = v;
        s1 += v;
        s2 += v * v;
    }
    part[0][q][t] = s1;
    part[1][q][t] = s2;
    __syncthreads();
    if (tid < 64) {
        float a = 0.f, b = 0.f;
#pragma unroll
        for (int qq = 0; qq < 4; ++qq) { a += part[0][qq][tid]; b += part[1][qq][tid]; }
        float mu = a * (1.f / 256.f);
        float var = b * (1.f / 256.f) - mu * mu;
        stat[0][tid] = mu;
        stat[1][tid] = rsqrtf(var + LN_EPS);
    }
    __syncthreads();
    float mu = stat[0][t], rs = stat[1][t];
    // normalize, gamma/beta, pack bf16, swizzled LDS write
#pragma unroll
    for (int jj = 0; jj < 8; ++jj) {
        union { bf8_t v; unsigned short u[8]; } pk;
#pragma unroll
        for (int e = 0; e < 8; ++e) {
            int c = q * 64 + jj * 8 + e;
            float y = (xv[jj * 8 + e] - mu) * rs * ln1g[c] + ln1b[c];
            pk.u[e] = f2bf(y);
        }
        int byte = t * 512 + ((q * 128 + jj * 16) ^ ((t & 7) << 4));
        *reinterpret_cast<bf8_t*>(reinterpret_cast<char*>(xt) + byte) = pk.v;
    }
    __syncthreads();

    // ---- MFMA phase (no barriers: waves own disjoint 16-row slices) ----
    int m0 = q * 16;
    int lm = lane & 15, lk = lane >> 4;
    int ta = m0 + lm;
    // preload A-fragments of x (k = 0..255, 8 k-tiles)
    bf8_t ax[8];
#pragma unroll
    for (int kb = 0; kb < 8; ++kb) {
        int byte = ta * 512 + ((((kb * 32 + lk * 8) * 2)) ^ ((ta & 7) << 4));
        ax[kb] = *reinterpret_cast<const bf8_t*>(reinterpret_cast<const char*>(xt) + byte);
    }
    f4_t oacc[16];
#pragma unroll
    for (int i = 0; i < 16; ++i) oacc[i] = (f4_t){0.f, 0.f, 0.f, 0.f};

    for (int fc = 0; fc < 8; ++fc) {
        int fbase0 = fc * 128;
        // GEMM1: h[16 x 128] = x[16 x 256] @ W1^T
        f4_t hacc[8];
#pragma unroll
        for (int i = 0; i < 8; ++i) hacc[i] = (f4_t){0.f, 0.f, 0.f, 0.f};
#pragma unroll
        for (int nt = 0; nt < 8; ++nt) {
            int f = fbase0 + nt * 16 + lm;
            const char* wrow = reinterpret_cast<const char*>(W1b + (size_t)f * 256);
#pragma unroll
            for (int kb = 0; kb < 8; ++kb) {
                bf8_t bfr = *reinterpret_cast<const bf8_t*>(wrow + (kb * 32 + lk * 8) * 2);
                hacc[nt] = __builtin_amdgcn_mfma_f32_16x16x32_bf16(ax[kb], bfr, hacc[nt], 0, 0, 0);
            }
        }
        // bias + exact GELU + bf16 -> swizzled ht
#pragma unroll
        for (int nt = 0; nt < 8; ++nt) {
            int f = fbase0 + nt * 16 + lm;
            float bias = b1[f];
            int fl = nt * 16 + lm;
#pragma unroll
            for (int j = 0; j < 4; ++j) {
                int trow = m0 + lk * 4 + j;
                float hv = hacc[nt][j] + bias;
                float g = 0.5f * hv * (1.f + erff(hv * 0.70710678f));
                int byte = trow * 256 + ((fl * 2) ^ ((trow & 7) << 4));
                *reinterpret_cast<unsigned short*>(reinterpret_cast<char*>(ht) + byte) = f2bf(g);
            }
        }
        // GEMM2 partial: out[16 x 256] += h[16 x 128] @ W2^T(chunk)
        bf8_t ah[4];
#pragma unroll
        for (int kb = 0; kb < 4; ++kb) {
            int byte = ta * 256 + ((((kb * 32 + lk * 8) * 2)) ^ ((ta & 7) << 4));
            ah[kb] = *reinterpret_cast<const bf8_t*>(reinterpret_cast<const char*>(ht) + byte);
        }
#pragma unroll
        for (int nt = 0; nt < 16; ++nt) {
            int cc = nt * 16 + lm;
            const char* wrow = reinterpret_cast<const char*>(W2b + (size_t)cc * 1024 + fbase0);
#pragma unroll
            for (int kb = 0; kb < 4; ++kb) {
                bf8_t bfr = *reinterpret_cast<const bf8_t*>(wrow + (kb * 32 + lk * 8) * 2);
                oacc[nt] = __builtin_amdgcn_mfma_f32_16x16x32_bf16(ah[kb], bfr, oacc[nt], 0, 0, 0);
            }
        }
    }

    // ---- epilogue: + b2 + residual2, LN2, store ----
    float sum_[4] = {0.f, 0.f, 0.f, 0.f};
    float sq_[4] = {0.f, 0.f, 0.f, 0.f};
#pragma unroll
    for (int nt = 0; nt < 16; ++nt) {
        int cc = nt * 16 + lm;
        float bb = b2[cc];
#pragma unroll
        for (int j = 0; j < 4; ++j) {
            int trow = m0 + lk * 4 + j;
            int byte = trow * 512 + ((cc * 2) ^ ((trow & 7) << 4));
            float res = bf2f(*reinterpret_cast<const unsigned short*>(
                reinterpret_cast<const char*>(xt) + byte));
            float v = oacc[nt][j] + bb + res;
            oacc[nt][j] = v;
            sum_[j] += v;
            sq_[j] += v * v;
        }
    }
#pragma unroll
    for (int d = 1; d < 16; d <<= 1) {
#pragma unroll
        for (int j = 0; j < 4; ++j) {
            sum_[j] += __shfl_xor(sum_[j], d, 64);
            sq_[j] += __shfl_xor(sq_[j], d, 64);
        }
    }
    float* obase = out + ((size_t)(n * 6400 + p0 + m0)) * 256;
#pragma unroll
    for (int j = 0; j < 4; ++j) {
        float mean = sum_[j] * (1.f / 256.f);
        float var = sq_[j] * (1.f / 256.f) - mean * mean;
        float rs2 = rsqrtf(var + LN_EPS);
        int trow = lk * 4 + j;
#pragma unroll
        for (int nt = 0; nt < 16; ++nt) {
            int cc = nt * 16 + lm;
            float v = (oacc[nt][j] - mean) * rs2 * ln2g[cc] + ln2b[cc];
            obase[(size_t)trow * 256 + cc] = v;
        }
    }
}

extern "C" void kernel_launch(void* const* d_in, const int* in_sizes, int n_in,
                              void* d_out, int out_size, void* d_ws, size_t ws_size,
                              hipStream_t stream) {
    const float* weight = (const float*)d_in[0];   // [8,400,400]
    const float* feature = (const float*)d_in[1];  // [8,256,80,80]
    const float* ln1g = (const float*)d_in[2];
    const float* ln1b = (const float*)d_in[3];
    const float* W1 = (const float*)d_in[4];       // [1024,256]
    const float* b1 = (const float*)d_in[5];
    const float* W2 = (const float*)d_in[6];       // [256,1024]
    const float* b2 = (const float*)d_in[7];
    const float* ln2g = (const float*)d_in[8];
    const float* ln2b = (const float*)d_in[9];
    float* outp = (float*)d_out;

    float* fs = (float*)d_ws;                         // 819200 f32
    float* rbuf = fs + 819200;                        // 819200 f32
    unsigned short* W1b = (unsigned short*)(rbuf + 819200);  // 262144 bf16
    unsigned short* W2b = W1b + 262144;                      // 262144 bf16

    cvt_kernel<<<1024, 256, 0, stream>>>(W1, W2, W1b, W2b);
    pool_kernel<<<3200, 256, 0, stream>>>(feature, fs);
    att_kernel<<<400, 256, 0, stream>>>(weight, fs, rbuf);
    main_kernel<<<800, 256, 0, stream>>>(feature, rbuf, ln1g, ln1b, W1b, b1,
                                         W2b, b2, ln2g, ln2b, outp);
}

// Round 2
// 246.155 us; speedup vs baseline: 2.5014x; 2.5014x over previous
//
#include <hip/hip_runtime.h>
#include <hip/hip_bf16.h>
#include <math.h>

#define LN_EPS 1e-5f

typedef __attribute__((ext_vector_type(4))) float f4_t;
typedef __attribute__((ext_vector_type(8))) short bf8_t;

__device__ __forceinline__ unsigned short f2bf(float x) {
    unsigned u = __builtin_bit_cast(unsigned, x);
    unsigned r = (u + 0x7FFFu + ((u >> 16) & 1u)) >> 16;
    return (unsigned short)r;
}
__device__ __forceinline__ float bf2f(unsigned short u) {
    return __builtin_bit_cast(float, ((unsigned)u) << 16);
}

// ---------------- kernel 1: reorder W1/W2 into MFMA-fragment-major bf16 -------
// W1f frag (ntf 0..63, kb 0..7): lane l holds W1[ntf*16+(l&15)][kb*32+(l>>4)*8 ..+8]
// W2f frag (ntc 0..15, kt 0..31): lane l holds W2[ntc*16+(l&15)][kt*32+(l>>4)*8 ..+8]
__global__ void cvt_kernel(const float* __restrict__ W1, const float* __restrict__ W2,
                           bf8_t* __restrict__ W1f, bf8_t* __restrict__ W2f) {
    int gid = blockIdx.x * 256 + threadIdx.x;   // 0..65535
    union { bf8_t v; unsigned short u[8]; } pk;
    if (gid < 32768) {
        int lane = gid & 63;
        int f = (gid >> 9) * 16 + (lane & 15);
        int k = ((gid >> 6) & 7) * 32 + (lane >> 4) * 8;
        const float* src = W1 + (size_t)f * 256 + k;
#pragma unroll
        for (int e = 0; e < 8; ++e) pk.u[e] = f2bf(src[e]);
        W1f[gid] = pk.v;
    } else {
        int g = gid - 32768;
        int lane = g & 63;
        int c = (g >> 11) * 16 + (lane & 15);
        int k = ((g >> 6) & 31) * 32 + (lane >> 4) * 8;
        const float* src = W2 + (size_t)c * 1024 + k;
#pragma unroll
        for (int e = 0; e < 8; ++e) pk.u[e] = f2bf(src[e]);
        W2f[g] = pk.v;
    }
}

// ---------------- kernel 2: 4x4 block pool: fs[n][k][c] ------------------------
__global__ void pool_kernel(const float* __restrict__ feature, float* __restrict__ fs) {
    int bk = blockIdx.x;           // n*400 + k
    int n = bk / 400, k = bk % 400;
    int c = threadIdx.x;
    int h = k / 20, w = k % 20;
    const float* base = feature + ((size_t)(n * 256 + c)) * 6400 + (h * 4) * 80 + w * 4;
    float s = 0.f;
#pragma unroll
    for (int dh = 0; dh < 4; ++dh) {
        float4 v = *reinterpret_cast<const float4*>(base + dh * 80);
        s += v.x + v.y + v.z + v.w;
    }
    fs[((size_t)n * 400 + k) * 256 + c] = s;
}

// ---------------- kernel 3: r[n][i][c] = sum_k weight[n][i][k] * fs[n][k][c] ---
__global__ void att_kernel(const float* __restrict__ wgt, const float* __restrict__ fs,
                           float* __restrict__ r) {
    __shared__ float fsl[16][256];
    __shared__ float wl[8][16];
    int b = blockIdx.x;
    int n = b / 50, i0 = (b % 50) * 8;
    int tid = threadIdx.x;
    const float* wbase = wgt + (size_t)n * 400 * 400;
    const float* fsbase = fs + (size_t)n * 400 * 256;
    float acc[8] = {0.f, 0.f, 0.f, 0.f, 0.f, 0.f, 0.f, 0.f};
    for (int k0 = 0; k0 < 400; k0 += 16) {
#pragma unroll
        for (int jj = 0; jj < 16; ++jj)
            fsl[jj][tid] = fsbase[(size_t)(k0 + jj) * 256 + tid];
        if (tid < 128)
            wl[tid >> 4][tid & 15] = wbase[(size_t)(i0 + (tid >> 4)) * 400 + k0 + (tid & 15)];
        __syncthreads();
#pragma unroll
        for (int kk = 0; kk < 16; ++kk) {
            float f = fsl[kk][tid];
#pragma unroll
            for (int ii = 0; ii < 8; ++ii) acc[ii] += wl[ii][kk] * f;
        }
        __syncthreads();
    }
#pragma unroll
    for (int ii = 0; ii < 8; ++ii)
        r[((size_t)n * 400 + i0 + ii) * 256 + tid] = acc[ii];
}

// ---------------- kernel 4: fused residual+att + LN1 + MLP(GELU) + LN2 ---------
// 64 tokens/block, 256 threads = 4 waves. Waves split the N-dim of each GEMM so
// every B-fragment (coalesced 1KB load from fragment-major W) feeds 4 MFMAs.
__global__ __launch_bounds__(256, 2) void main_kernel(
    const float* __restrict__ feat, const float* __restrict__ r,
    const float* __restrict__ ln1g, const float* __restrict__ ln1b,
    const bf8_t* __restrict__ W1f, const float* __restrict__ b1,
    const bf8_t* __restrict__ W2f, const float* __restrict__ b2,
    const float* __restrict__ ln2g, const float* __restrict__ ln2b,
    float* __restrict__ out) {
    __shared__ unsigned short xt[64 * 256];   // [t][c] swizzled, 32 KB
    __shared__ unsigned short ht[64 * 128];   // [t][f] swizzled, 16 KB
    __shared__ float psum[4][64], psq[4][64];
    __shared__ float stat[2][64];

    int bid = blockIdx.x;
    int n = bid / 100;
    int p0 = (bid % 100) * 64;
    int tid = threadIdx.x;
    int lane = tid & 63;
    int q = tid >> 6;                     // wave id
    int t = lane;                         // token row this thread loads in phase 1
    int p = p0 + t;
    int iatt = ((p / 80) >> 2) * 20 + ((p % 80) >> 2);

    // ---- phase 1: x = residual + att, LN1 ----
    const float* fbase = feat + ((size_t)(n * 256 + q * 64)) * 6400 + p;
    const float* rrow = r + ((size_t)(n * 400 + iatt)) * 256 + q * 64;
    float xv[64];
    float s1 = 0.f, s2 = 0.f;
#pragma unroll
    for (int j = 0; j < 64; ++j) {
        float v = fbase[(size_t)j * 6400] + rrow[j];
        xv[j] = v;
        s1 += v;
        s2 += v * v;
    }
    psum[q][t] = s1;
    psq[q][t] = s2;
    __syncthreads();
    if (tid < 64) {
        float a = psum[0][tid] + psum[1][tid] + psum[2][tid] + psum[3][tid];
        float b = psq[0][tid] + psq[1][tid] + psq[2][tid] + psq[3][tid];
        float mu = a * (1.f / 256.f);
        float var = b * (1.f / 256.f) - mu * mu;
        stat[0][tid] = mu;
        stat[1][tid] = rsqrtf(var + LN_EPS);
    }
    __syncthreads();
    float mu = stat[0][t], rs = stat[1][t];
#pragma unroll
    for (int jj = 0; jj < 8; ++jj) {
        union { bf8_t v; unsigned short u[8]; } pk;
#pragma unroll
        for (int e = 0; e < 8; ++e) {
            int c = q * 64 + jj * 8 + e;
            float y = (xv[jj * 8 + e] - mu) * rs * ln1g[c] + ln1b[c];
            pk.u[e] = f2bf(y);
        }
        int byte = t * 512 + ((q * 128 + jj * 16) ^ ((t & 7) << 4));
        *reinterpret_cast<bf8_t*>(reinterpret_cast<char*>(xt) + byte) = pk.v;
    }
    __syncthreads();

    // ---- MFMA phase ----
    int lm = lane & 15, lk = lane >> 4;
    const char* xtb = reinterpret_cast<const char*>(xt);
    const char* htb = reinterpret_cast<const char*>(ht);
    char* htw = reinterpret_cast<char*>(ht);

    f4_t oacc[16];   // [m][cl]
#pragma unroll
    for (int i = 0; i < 16; ++i) oacc[i] = (f4_t){0.f, 0.f, 0.f, 0.f};

    for (int fc = 0; fc < 8; ++fc) {
        // GEMM1: h[64 x 128] chunk; wave q owns f-tiles {2q, 2q+1}
        f4_t hacc[8];   // [m][ntl]
#pragma unroll
        for (int i = 0; i < 8; ++i) hacc[i] = (f4_t){0.f, 0.f, 0.f, 0.f};
        const bf8_t* w1p = W1f + (size_t)(fc * 8 + 2 * q) * 8 * 64 + lane;
#pragma unroll
        for (int kb = 0; kb < 8; ++kb) {
            bf8_t bf0 = w1p[kb * 64];
            bf8_t bf1 = w1p[512 + kb * 64];
#pragma unroll
            for (int m = 0; m < 4; ++m) {
                int row = m * 16 + lm;
                bf8_t a = *reinterpret_cast<const bf8_t*>(
                    xtb + row * 512 + ((kb * 64 + lk * 16) ^ ((row & 7) << 4)));
                hacc[m * 2] = __builtin_amdgcn_mfma_f32_16x16x32_bf16(a, bf0, hacc[m * 2], 0, 0, 0);
                hacc[m * 2 + 1] = __builtin_amdgcn_mfma_f32_16x16x32_bf16(a, bf1, hacc[m * 2 + 1], 0, 0, 0);
            }
        }
        __syncthreads();   // previous fc's GEMM2 reads of ht are done
        // bias + exact GELU -> swizzled ht
#pragma unroll
        for (int ntl = 0; ntl < 2; ++ntl) {
            int fl = (2 * q + ntl) * 16 + lm;       // 0..127 within chunk
            float bias = b1[fc * 128 + fl];
#pragma unroll
            for (int m = 0; m < 4; ++m) {
#pragma unroll
                for (int j = 0; j < 4; ++j) {
                    int row = m * 16 + lk * 4 + j;
                    float hv = hacc[m * 2 + ntl][j] + bias;
                    float g = 0.5f * hv * (1.f + erff(hv * 0.70710678f));
                    *reinterpret_cast<unsigned short*>(
                        htw + row * 256 + ((fl * 2) ^ ((row & 7) << 4))) = f2bf(g);
                }
            }
        }
        __syncthreads();
        // GEMM2 partial: out[64 x 256] += h @ W2^T(chunk); wave q owns c-tiles 4q..4q+3
        const bf8_t* w2p = W2f + (size_t)(4 * q * 32 + fc * 4) * 64 + lane;
#pragma unroll
        for (int kb = 0; kb < 4; ++kb) {
            bf8_t bb0 = w2p[kb * 64];
            bf8_t bb1 = w2p[(32 + kb) * 64];
            bf8_t bb2 = w2p[(64 + kb) * 64];
            bf8_t bb3 = w2p[(96 + kb) * 64];
#pragma unroll
            for (int m = 0; m < 4; ++m) {
                int row = m * 16 + lm;
                bf8_t a = *reinterpret_cast<const bf8_t*>(
                    htb + row * 256 + ((kb * 64 + lk * 16) ^ ((row & 7) << 4)));
                oacc[m * 4 + 0] = __builtin_amdgcn_mfma_f32_16x16x32_bf16(a, bb0, oacc[m * 4 + 0], 0, 0, 0);
                oacc[m * 4 + 1] = __builtin_amdgcn_mfma_f32_16x16x32_bf16(a, bb1, oacc[m * 4 + 1], 0, 0, 0);
                oacc[m * 4 + 2] = __builtin_amdgcn_mfma_f32_16x16x32_bf16(a, bb2, oacc[m * 4 + 2], 0, 0, 0);
                oacc[m * 4 + 3] = __builtin_amdgcn_mfma_f32_16x16x32_bf16(a, bb3, oacc[m * 4 + 3], 0, 0, 0);
            }
        }
    }

    // ---- epilogue: + b2 + residual2, LN2, store ----
    float b2l[4];
#pragma unroll
    for (int cl = 0; cl < 4; ++cl) b2l[cl] = b2[(4 * q + cl) * 16 + lm];
#pragma unroll
    for (int m = 0; m < 4; ++m) {
#pragma unroll
        for (int j = 0; j < 4; ++j) {
            int row = m * 16 + lk * 4 + j;
            float s = 0.f, ss = 0.f;
#pragma unroll
            for (int cl = 0; cl < 4; ++cl) {
                int c = (4 * q + cl) * 16 + lm;
                float res = bf2f(*reinterpret_cast<const unsigned short*>(
                    xtb + row * 512 + ((c * 2) ^ ((row & 7) << 4))));
                float v = oacc[m * 4 + cl][j] + b2l[cl] + res;
                oacc[m * 4 + cl][j] = v;
                s += v;
                ss += v * v;
            }
#pragma unroll
            for (int d = 1; d < 16; d <<= 1) {
                s += __shfl_xor(s, d, 64);
                ss += __shfl_xor(ss, d, 64);
            }
            if (lm == 0) { psum[q][row] = s; psq[q][row] = ss; }
        }
    }
    __syncthreads();
    if (tid < 64) {
        float a = psum[0][tid] + psum[1][tid] + psum[2][tid] + psum[3][tid];
        float b = psq[0][tid] + psq[1][tid] + psq[2][tid] + psq[3][tid];
        float mu2 = a * (1.f / 256.f);
        float var = b * (1.f / 256.f) - mu2 * mu2;
        stat[0][tid] = mu2;
        stat[1][tid] = rsqrtf(var + LN_EPS);
    }
    __syncthreads();
    float g2[4], be2[4];
#pragma unroll
    for (int cl = 0; cl < 4; ++cl) {
        int c = (4 * q + cl) * 16 + lm;
        g2[cl] = ln2g[c];
        be2[cl] = ln2b[c];
    }
    float* obase = out + ((size_t)(n * 6400 + p0)) * 256;
#pragma unroll
    for (int m = 0; m < 4; ++m) {
#pragma unroll
        for (int j = 0; j < 4; ++j) {
            int row = m * 16 + lk * 4 + j;
            float mu2 = stat[0][row], r2 = stat[1][row];
#pragma unroll
            for (int cl = 0; cl < 4; ++cl) {
                int c = (4 * q + cl) * 16 + lm;
                obase[(size_t)row * 256 + c] =
                    (oacc[m * 4 + cl][j] - mu2) * r2 * g2[cl] + be2[cl];
            }
        }
    }
}

extern "C" void kernel_launch(void* const* d_in, const int* in_sizes, int n_in,
                              void* d_out, int out_size, void* d_ws, size_t ws_size,
                              hipStream_t stream) {
    const float* weight = (const float*)d_in[0];   // [8,400,400]
    const float* feature = (const float*)d_in[1];  // [8,256,80,80]
    const float* ln1g = (const float*)d_in[2];
    const float* ln1b = (const float*)d_in[3];
    const float* W1 = (const float*)d_in[4];       // [1024,256]
    const float* b1 = (const float*)d_in[5];
    const float* W2 = (const float*)d_in[6];       // [256,1024]
    const float* b2 = (const float*)d_in[7];
    const float* ln2g = (const float*)d_in[8];
    const float* ln2b = (const float*)d_in[9];
    float* outp = (float*)d_out;

    float* fs = (float*)d_ws;                         // 819200 f32
    float* rbuf = fs + 819200;                        // 819200 f32
    bf8_t* W1f = (bf8_t*)(rbuf + 819200);             // 32768 frags (512 KB)
    bf8_t* W2f = W1f + 32768;                         // 32768 frags (512 KB)

    cvt_kernel<<<256, 256, 0, stream>>>(W1, W2, W1f, W2f);
    pool_kernel<<<3200, 256, 0, stream>>>(feature, fs);
    att_kernel<<<400, 256, 0, stream>>>(weight, fs, rbuf);
    main_kernel<<<800, 256, 0, stream>>>(feature, rbuf, ln1g, ln1b, W1f, b1,
                                         W2f, b2, ln2g, ln2b, outp);
}